// Round 1
// baseline (3495.750 us; speedup 1.0000x reference)
//
#include <hip/hip_runtime.h>
#include <math.h>

#define BB 4
#define CC 512
#define HH 48
#define WW 48
#define NN 2304      // H*W
#define DDQ 64       // C/8
#define TILE 64
#define BK 16

// ---------------------------------------------------------------------------
// Shared-tile loaders. dst is [BK][TILE]. 256 threads, float4 per thread.
// load_kx: src[k][x], contiguous in x (inner dim). Direct copy.
// load_xk: src[x][k], contiguous in k. Transposes into dst[k][x].
// ---------------------------------------------------------------------------
__device__ __forceinline__ void load_kx(float dst[BK][TILE], const float* __restrict__ src,
                                        int ld, int k0, int x0, int tid) {
    int r = tid >> 4;            // 0..15  (k)
    int c = (tid & 15) << 2;     // 0..60  (x)
    float4 v = *reinterpret_cast<const float4*>(src + (size_t)(k0 + r) * ld + x0 + c);
    *reinterpret_cast<float4*>(&dst[r][c]) = v;
}

__device__ __forceinline__ void load_xk(float dst[BK][TILE], const float* __restrict__ src,
                                        int ld, int x0, int k0, int tid) {
    int x  = tid >> 2;           // 0..63
    int kb = (tid & 3) << 2;     // 0,4,8,12
    float4 v = *reinterpret_cast<const float4*>(src + (size_t)(x0 + x) * ld + k0 + kb);
    dst[kb + 0][x] = v.x;
    dst[kb + 1][x] = v.y;
    dst[kb + 2][x] = v.z;
    dst[kb + 3][x] = v.w;
}

#define GEMM_MICRO(As, Bs, acc, ty4, tx4)                                   \
    _Pragma("unroll")                                                       \
    for (int kkk = 0; kkk < BK; ++kkk) {                                    \
        float av0 = As[kkk][ty4 + 0], av1 = As[kkk][ty4 + 1];               \
        float av2 = As[kkk][ty4 + 2], av3 = As[kkk][ty4 + 3];               \
        float bv0 = Bs[kkk][tx4 + 0], bv1 = Bs[kkk][tx4 + 1];               \
        float bv2 = Bs[kkk][tx4 + 2], bv3 = Bs[kkk][tx4 + 3];               \
        acc[0][0] = fmaf(av0, bv0, acc[0][0]);                              \
        acc[0][1] = fmaf(av0, bv1, acc[0][1]);                              \
        acc[0][2] = fmaf(av0, bv2, acc[0][2]);                              \
        acc[0][3] = fmaf(av0, bv3, acc[0][3]);                              \
        acc[1][0] = fmaf(av1, bv0, acc[1][0]);                              \
        acc[1][1] = fmaf(av1, bv1, acc[1][1]);                              \
        acc[1][2] = fmaf(av1, bv2, acc[1][2]);                              \
        acc[1][3] = fmaf(av1, bv3, acc[1][3]);                              \
        acc[2][0] = fmaf(av2, bv0, acc[2][0]);                              \
        acc[2][1] = fmaf(av2, bv1, acc[2][1]);                              \
        acc[2][2] = fmaf(av2, bv2, acc[2][2]);                              \
        acc[2][3] = fmaf(av2, bv3, acc[2][3]);                              \
        acc[3][0] = fmaf(av3, bv0, acc[3][0]);                              \
        acc[3][1] = fmaf(av3, bv1, acc[3][1]);                              \
        acc[3][2] = fmaf(av3, bv2, acc[3][2]);                              \
        acc[3][3] = fmaf(av3, bv3, acc[3][3]);                              \
    }

// ---------------------------------------------------------------------------
// conv1x1 as GEMM: out[b][i][j] = sum_k W[i][k] * X[b][k][j] + bias[i]
// EPI==1: out = sigmoid(acc + bias) * gate[b][i][j]   (gate == same layout)
// ---------------------------------------------------------------------------
template <int EPI>
__global__ __launch_bounds__(256) void gemm_conv1x1(
        const float* __restrict__ W, const float* __restrict__ X,
        const float* __restrict__ bias, const float* __restrict__ gate,
        float* __restrict__ out, int Kdim) {
    __shared__ float As[BK][TILE];
    __shared__ float Bs[BK][TILE];
    int tid = threadIdx.x;
    int j0 = blockIdx.x * TILE;
    int i0 = blockIdx.y * TILE;
    int b  = blockIdx.z;
    int M  = gridDim.y * TILE;
    const float* Xb = X + (size_t)b * Kdim * NN;
    float acc[4][4] = {};
    int ty4 = (tid >> 4) << 2;
    int tx4 = (tid & 15) << 2;
    for (int kc = 0; kc < Kdim; kc += BK) {
        load_xk(As, W, Kdim, i0, kc, tid);
        load_kx(Bs, Xb, NN, kc, j0, tid);
        __syncthreads();
        GEMM_MICRO(As, Bs, acc, ty4, tx4);
        __syncthreads();
    }
#pragma unroll
    for (int ii = 0; ii < 4; ++ii) {
        int i = i0 + ty4 + ii;
        float bi = bias[i];
#pragma unroll
        for (int jj = 0; jj < 4; ++jj) {
            int j = j0 + tx4 + jj;
            size_t idx = ((size_t)b * M + i) * NN + j;
            float val = acc[ii][jj] + bi;
            if (EPI == 1) {
                val = gate[idx] / (1.f + __expf(-val));
            }
            out[idx] = val;
        }
    }
}

// ---------------------------------------------------------------------------
// energy: E[b][i=n][j=m] = sum_d Q[b][d][i] * K[b][d][j]   (Kdim = 64)
// ---------------------------------------------------------------------------
__global__ __launch_bounds__(256) void gemm_energy(
        const float* __restrict__ Q, const float* __restrict__ Kk,
        float* __restrict__ E) {
    __shared__ float As[BK][TILE];
    __shared__ float Bs[BK][TILE];
    int tid = threadIdx.x;
    int j0 = blockIdx.x * TILE;
    int i0 = blockIdx.y * TILE;
    int b  = blockIdx.z;
    const float* Qb = Q + (size_t)b * DDQ * NN;
    const float* Kb = Kk + (size_t)b * DDQ * NN;
    float acc[4][4] = {};
    int ty4 = (tid >> 4) << 2;
    int tx4 = (tid & 15) << 2;
    for (int kc = 0; kc < DDQ; kc += BK) {
        load_kx(As, Qb, NN, kc, i0, tid);
        load_kx(Bs, Kb, NN, kc, j0, tid);
        __syncthreads();
        GEMM_MICRO(As, Bs, acc, ty4, tx4);
        __syncthreads();
    }
#pragma unroll
    for (int ii = 0; ii < 4; ++ii) {
        int i = i0 + ty4 + ii;
#pragma unroll
        for (int jj = 0; jj < 4; ++jj) {
            int j = j0 + tx4 + jj;
            E[((size_t)b * NN + i) * NN + j] = acc[ii][jj];
        }
    }
}

// ---------------------------------------------------------------------------
// attention apply: out[b][i=c][j=m] = sum_n V[b][i][n] * A[b][j][n]
// ---------------------------------------------------------------------------
__global__ __launch_bounds__(256) void gemm_attn(
        const float* __restrict__ V, const float* __restrict__ A,
        float* __restrict__ out) {
    __shared__ float As[BK][TILE];
    __shared__ float Bs[BK][TILE];
    int tid = threadIdx.x;
    int j0 = blockIdx.x * TILE;
    int i0 = blockIdx.y * TILE;
    int b  = blockIdx.z;
    int M  = gridDim.y * TILE;
    const float* Vb = V + (size_t)b * CC * NN;
    const float* Ab = A + (size_t)b * NN * NN;
    float acc[4][4] = {};
    int ty4 = (tid >> 4) << 2;
    int tx4 = (tid & 15) << 2;
    for (int kc = 0; kc < NN; kc += BK) {
        load_xk(As, Vb, NN, i0, kc, tid);
        load_xk(Bs, Ab, NN, j0, kc, tid);
        __syncthreads();
        GEMM_MICRO(As, Bs, acc, ty4, tx4);
        __syncthreads();
    }
#pragma unroll
    for (int ii = 0; ii < 4; ++ii) {
        int i = i0 + ty4 + ii;
#pragma unroll
        for (int jj = 0; jj < 4; ++jj) {
            int j = j0 + tx4 + jj;
            out[((size_t)b * M + i) * NN + j] = acc[ii][jj];
        }
    }
}

// ---------------------------------------------------------------------------
// 3x3 conv (SAME) as implicit GEMM over K = C*9 = 4608, fused BN + ReLU.
// out[b][co][m] = relu( (sum W9[co][k]*patch[k][m]) * scale[co] + shift[co] )
// ---------------------------------------------------------------------------
__global__ __launch_bounds__(256) void conv3x3_bn_relu(
        const float* __restrict__ in, const float* __restrict__ w9,
        const float* __restrict__ g, const float* __restrict__ beta,
        const float* __restrict__ mu, const float* __restrict__ var,
        float* __restrict__ out) {
    __shared__ float As[BK][TILE];
    __shared__ float Bs[BK][TILE];
    int tid = threadIdx.x;
    int j0 = blockIdx.x * TILE;   // spatial m
    int i0 = blockIdx.y * TILE;   // co
    int b  = blockIdx.z;
    const int KD = CC * 9;
    float acc[4][4] = {};
    int ty4 = (tid >> 4) << 2;
    int tx4 = (tid & 15) << 2;
    for (int kc = 0; kc < KD; kc += BK) {
        load_xk(As, w9, KD, i0, kc, tid);
        // im2col B-tile: Bs[kk][mm]
        {
            int kk = kc + (tid >> 4);
            int ci = kk / 9;
            int r  = kk - ci * 9;
            int dh = r / 3 - 1;
            int dw = r - (r / 3) * 3 - 1;
            const float* inb = in + ((size_t)b * CC + ci) * NN;
            int mb = j0 + ((tid & 15) << 2);
#pragma unroll
            for (int e = 0; e < 4; ++e) {
                int m = mb + e;
                int hh = m / WW;
                int ww = m - hh * WW;
                int h2 = hh + dh;
                int w2 = ww + dw;
                float val = 0.f;
                if ((unsigned)h2 < (unsigned)HH && (unsigned)w2 < (unsigned)WW)
                    val = inb[h2 * WW + w2];
                Bs[tid >> 4][((tid & 15) << 2) + e] = val;
            }
        }
        __syncthreads();
        GEMM_MICRO(As, Bs, acc, ty4, tx4);
        __syncthreads();
    }
#pragma unroll
    for (int ii = 0; ii < 4; ++ii) {
        int co = i0 + ty4 + ii;
        float sc = g[co] * rsqrtf(var[co] + 1e-5f);
        float sh = beta[co] - mu[co] * sc;
#pragma unroll
        for (int jj = 0; jj < 4; ++jj) {
            int j = j0 + tx4 + jj;
            float v = acc[ii][jj] * sc + sh;
            out[((size_t)b * CC + co) * NN + j] = v > 0.f ? v : 0.f;
        }
    }
}

// ---------------------------------------------------------------------------
// Row softmax over E[b][n][:], optional analytic Chebyshev mask (radius<0 = dense).
// In-place. Grid = B*N rows, 256 threads.
// ---------------------------------------------------------------------------
__global__ __launch_bounds__(256) void softmax_rows(float* __restrict__ E, int radius) {
    __shared__ float red[256];
    int tid = threadIdx.x;
    size_t row = blockIdx.x;
    int m = (int)(row % NN);          // query index within image
    float* e = E + row * (size_t)NN;

    float lm = -1e30f;
    for (int n = tid; n < NN; n += 256) lm = fmaxf(lm, e[n]);
    red[tid] = lm;
    __syncthreads();
    for (int s = 128; s > 0; s >>= 1) {
        if (tid < s) red[tid] = fmaxf(red[tid], red[tid + s]);
        __syncthreads();
    }
    float mx = red[0];
    __syncthreads();

    int mr = m / WW, mc = m - (m / WW) * WW;
    float ls = 0.f;
    for (int n = tid; n < NN; n += 256) {
        float wv = __expf(e[n] - mx);
        if (radius >= 0) {
            int nr = n / WW, nc = n - (n / WW) * WW;
            int dr = mr - nr; if (dr < 0) dr = -dr;
            int dc = mc - nc; if (dc < 0) dc = -dc;
            int d = dr > dc ? dr : dc;
            if (d > radius) wv = 0.f;
        }
        e[n] = wv;
        ls += wv;
    }
    red[tid] = ls;
    __syncthreads();
    for (int s = 128; s > 0; s >>= 1) {
        if (tid < s) red[tid] += red[tid + s];
        __syncthreads();
    }
    float inv = 1.f / red[0];
    for (int n = tid; n < NN; n += 256) e[n] *= inv;
}

// ---------------------------------------------------------------------------
// out[i] = gamma[0]*a[i] + r[i]   (out may alias a)
// ---------------------------------------------------------------------------
__global__ __launch_bounds__(256) void residual_kernel(
        float* __restrict__ out, const float* __restrict__ a,
        const float* __restrict__ r, const float* __restrict__ gamma, int n) {
    int i = blockIdx.x * 256 + threadIdx.x;
    if (i < n) out[i] = gamma[0] * a[i] + r[i];
}

// ---------------------------------------------------------------------------
extern "C" void kernel_launch(void* const* d_in, const int* in_sizes, int n_in,
                              void* d_out, int out_size, void* d_ws, size_t ws_size,
                              hipStream_t stream) {
    const float* x    = (const float*)d_in[0];
    const float* Wq   = (const float*)d_in[1];
    const float* bq   = (const float*)d_in[2];
    const float* Wk   = (const float*)d_in[3];
    const float* bk   = (const float*)d_in[4];
    const float* Wv   = (const float*)d_in[5];
    const float* bv   = (const float*)d_in[6];
    const float* c1w  = (const float*)d_in[7];
    const float* bn1w = (const float*)d_in[8];
    const float* bn1b = (const float*)d_in[9];
    const float* bn1m = (const float*)d_in[10];
    const float* bn1v = (const float*)d_in[11];
    const float* c2w  = (const float*)d_in[12];
    const float* bn2w = (const float*)d_in[13];
    const float* bn2b = (const float*)d_in[14];
    const float* bn2m = (const float*)d_in[15];
    const float* bn2v = (const float*)d_in[16];
    const float* s1w  = (const float*)d_in[17];
    const float* s1b  = (const float*)d_in[18];
    const float* s2w  = (const float*)d_in[19];
    const float* s2b  = (const float*)d_in[20];
    const float* gamma  = (const float*)d_in[21];
    const float* gamma1 = (const float*)d_in[22];
    const float* gamma2 = (const float*)d_in[23];
    // d_in[24], d_in[25] (masks) unused: mask computed analytically.

    float* out = (float*)d_out;
    float* ws  = (float*)d_ws;

    const size_t szQK = (size_t)BB * DDQ * NN;   // 589,824
    const size_t szC  = (size_t)BB * CC * NN;    // 4,718,592
    const size_t szA  = (size_t)BB * NN * NN;    // 21,233,664

    float* q    = ws;
    float* kk   = q + szQK;
    float* v    = kk + szQK;
    float* t0   = v + szC;
    float* t1   = t0 + szC;
    float* t2   = t1 + szC;
    float* attn = t2 + szC;
    // total = 2*szQK + 4*szC + szA = 41,287,680 floats ≈ 157.5 MiB

    dim3 blk(256);
    dim3 gQK(NN / TILE, DDQ / TILE, BB);   // (36, 1, 4)
    dim3 gC (NN / TILE, CC / TILE, BB);    // (36, 8, 4)
    dim3 gE (NN / TILE, NN / TILE, BB);    // (36, 36, 4)
    dim3 gSm(BB * NN);                     // 9216 rows
    int nel = (int)szC;
    dim3 gR (nel / 256);

    // q, k, v projections
    gemm_conv1x1<0><<<gQK, blk, 0, stream>>>(Wq, x, bq, nullptr, q, CC);
    gemm_conv1x1<0><<<gQK, blk, 0, stream>>>(Wk, x, bk, nullptr, kk, CC);
    gemm_conv1x1<0><<<gC,  blk, 0, stream>>>(Wv, x, bv, nullptr, v, CC);

    // ---- stage 0: dense softmax attention ----
    gemm_energy<<<gE, blk, 0, stream>>>(q, kk, attn);
    softmax_rows<<<gSm, blk, 0, stream>>>(attn, -1);
    gemm_attn<<<gC, blk, 0, stream>>>(v, attn, t0);
    residual_kernel<<<gR, blk, 0, stream>>>(t0, t0, x, gamma, nel);
    conv3x3_bn_relu<<<gC, blk, 0, stream>>>(t0, c1w, bn1w, bn1b, bn1m, bn1v, t1); // t1 = out0

    // ---- stage 1: radius-6 masked attention ----
    gemm_conv1x1<1><<<gC, blk, 0, stream>>>(s1w, t1, s1b, t1, t2, CC);            // t2 = s1
    gemm_energy<<<gE, blk, 0, stream>>>(q, kk, attn);
    softmax_rows<<<gSm, blk, 0, stream>>>(attn, 6);
    gemm_attn<<<gC, blk, 0, stream>>>(t2, attn, t0);
    residual_kernel<<<gR, blk, 0, stream>>>(t0, t0, t1, gamma1, nel);
    conv3x3_bn_relu<<<gC, blk, 0, stream>>>(t0, c2w, bn2w, bn2b, bn2m, bn2v, t2); // t2 = out1

    // ---- stage 2: radius-12 masked attention ----
    gemm_conv1x1<1><<<gC, blk, 0, stream>>>(s2w, t2, s2b, t2, t1, CC);            // t1 = s2
    gemm_energy<<<gE, blk, 0, stream>>>(q, kk, attn);
    softmax_rows<<<gSm, blk, 0, stream>>>(attn, 12);
    gemm_attn<<<gC, blk, 0, stream>>>(t1, attn, out);
    residual_kernel<<<gR, blk, 0, stream>>>(out, out, t2, gamma2, nel);
}

// Round 4
// 665.697 us; speedup vs baseline: 5.2513x; 5.2513x over previous
//
#include <hip/hip_runtime.h>
#include <math.h>

#define BB 4
#define CC 512
#define HH 48
#define WW 48
#define NN 2304      // H*W
#define DDQ 64       // C/8
#define LDSP 72      // padded LDS row stride (fp16 elems): 144B, 16B-aligned

typedef __attribute__((ext_vector_type(4))) float f32x4;
typedef __attribute__((ext_vector_type(8))) _Float16 half8;
typedef __attribute__((ext_vector_type(4))) _Float16 half4;

__device__ __forceinline__ int imax(int a, int b) { return a > b ? a : b; }
__device__ __forceinline__ int imin(int a, int b) { return a < b ? a : b; }

// Stage 64 rows x 64 fp16 (k-contiguous) from global [x][k] into LDS [64][LDSP].
__device__ __forceinline__ void stage_rows(_Float16* dst, const _Float16* __restrict__ src,
                                           int ld, int row0, int k0, int tid) {
#pragma unroll
    for (int i = 0; i < 2; ++i) {
        int s = tid * 2 + i;
        int r = s >> 3, off = (s & 7) << 3;
        *(half8*)(dst + r * LDSP + off) =
            *(const half8*)(src + (size_t)(row0 + r) * ld + k0 + off);
    }
}

// One 64-deep K step: 4 waves each compute 32x32 (2x2 of 16x16x32 MFMA tiles).
__device__ __forceinline__ void mfma_tile(const _Float16* As, const _Float16* Bs,
                                          f32x4 acc[2][2], int wm, int wn, int x, int qq) {
#pragma unroll
    for (int ks = 0; ks < 2; ++ks) {
        int kof = ks * 32 + qq * 8;
        half8 a0 = *(const half8*)(As + (wm + x) * LDSP + kof);
        half8 a1 = *(const half8*)(As + (wm + 16 + x) * LDSP + kof);
        half8 b0 = *(const half8*)(Bs + (wn + x) * LDSP + kof);
        half8 b1 = *(const half8*)(Bs + (wn + 16 + x) * LDSP + kof);
        acc[0][0] = __builtin_amdgcn_mfma_f32_16x16x32_f16(a0, b0, acc[0][0], 0, 0, 0);
        acc[0][1] = __builtin_amdgcn_mfma_f32_16x16x32_f16(a0, b1, acc[0][1], 0, 0, 0);
        acc[1][0] = __builtin_amdgcn_mfma_f32_16x16x32_f16(a1, b0, acc[1][0], 0, 0, 0);
        acc[1][1] = __builtin_amdgcn_mfma_f32_16x16x32_f16(a1, b1, acc[1][1], 0, 0, 0);
    }
}

#define WAVE_IDX()                             \
    int tid = threadIdx.x;                     \
    int wave = tid >> 6, lane = tid & 63;      \
    int wm = (wave >> 1) * 32, wn = (wave & 1) * 32; \
    int x = lane & 15, qq = lane >> 4;

#define ACC_INIT()                             \
    f32x4 zf = {0.f, 0.f, 0.f, 0.f};           \
    f32x4 acc[2][2];                           \
    acc[0][0] = zf; acc[0][1] = zf; acc[1][0] = zf; acc[1][1] = zf;

// ------------------------- prep kernels -------------------------

__global__ __launch_bounds__(256) void k_f32_to_f16(const float* __restrict__ src,
                                                    _Float16* __restrict__ dst, int n) {
    for (int i = blockIdx.x * 256 + threadIdx.x; i < n; i += gridDim.x * 256)
        dst[i] = (_Float16)src[i];
}

// conv weight [co][ci][r=9] -> [r][co][ci] fp16
__global__ __launch_bounds__(256) void k_repack_conv(const float* __restrict__ w,
                                                     _Float16* __restrict__ dst) {
    int i = blockIdx.x * 256 + threadIdx.x;
    if (i >= 9 * CC * CC) return;
    int r = i / (CC * CC);
    int rem = i - r * CC * CC;
    int co = rem / CC, ci = rem - (rem / CC) * CC;
    dst[i] = (_Float16)w[((size_t)co * CC + ci) * 9 + r];
}

// x fp32 [b][c][n] -> xT fp16 [b][n][c]
__global__ __launch_bounds__(256) void k_transpose_x(const float* __restrict__ x,
                                                     _Float16* __restrict__ xT) {
    __shared__ float tile[32][33];
    int b = blockIdx.z;
    int c0 = blockIdx.y * 32, n0 = blockIdx.x * 32;
    int tx = threadIdx.x & 31, ty = threadIdx.x >> 5;  // 32 x 8
    const float* xb = x + (size_t)b * CC * NN;
#pragma unroll
    for (int rr = 0; rr < 32; rr += 8)
        tile[ty + rr][tx] = xb[(size_t)(c0 + ty + rr) * NN + n0 + tx];
    __syncthreads();
    _Float16* xTb = xT + (size_t)b * NN * CC;
#pragma unroll
    for (int rr = 0; rr < 32; rr += 8)
        xTb[(size_t)(n0 + ty + rr) * CC + c0 + tx] = (_Float16)tile[tx][ty + rr];
}

// ------------------------- q/k projection -------------------------
__global__ __launch_bounds__(256) void k_qkproj(const _Float16* __restrict__ Wq,
                                                const _Float16* __restrict__ Wk,
                                                const float* __restrict__ bq,
                                                const float* __restrict__ bk,
                                                const _Float16* __restrict__ xT,
                                                _Float16* __restrict__ qT,
                                                _Float16* __restrict__ kT) {
    __shared__ _Float16 As[64 * LDSP];
    __shared__ _Float16 Bs[64 * LDSP];
    WAVE_IDX();
    int j0 = blockIdx.x * 64, b = blockIdx.z;
    const _Float16* Wp = blockIdx.y ? Wk : Wq;
    const float* bias = blockIdx.y ? bk : bq;
    _Float16* outT = blockIdx.y ? kT : qT;
    const _Float16* xTb = xT + (size_t)b * NN * CC;
    ACC_INIT();
    for (int kc = 0; kc < CC; kc += 64) {
        stage_rows(As, Wp, CC, 0, kc, tid);
        stage_rows(Bs, xTb, CC, j0, kc, tid);
        __syncthreads();
        mfma_tile(As, Bs, acc, wm, wn, x, qq);
        __syncthreads();
    }
#pragma unroll
    for (int ms = 0; ms < 2; ++ms) {
        int R0 = wm + ms * 16 + qq * 4;   // d index
#pragma unroll
        for (int ns = 0; ns < 2; ++ns) {
            int Ccol = j0 + wn + ns * 16 + x;  // n index
            half4 t;
            t.x = (_Float16)(acc[ms][ns][0] + bias[R0 + 0]);
            t.y = (_Float16)(acc[ms][ns][1] + bias[R0 + 1]);
            t.z = (_Float16)(acc[ms][ns][2] + bias[R0 + 2]);
            t.w = (_Float16)(acc[ms][ns][3] + bias[R0 + 3]);
            *(half4*)(outT + ((size_t)b * NN + Ccol) * DDQ + R0) = t;
        }
    }
}

// ------------------------- C x C GEMM (v-proj and sigmoid gates) -------------------------
// EPI=0: out[c][n] = acc + bias.  EPI=1: out = sigmoid(acc+bias) * gate[c][n](fp32)
template <int EPI>
__global__ __launch_bounds__(256) void k_cgemm(const _Float16* __restrict__ W,
                                               const float* __restrict__ bias,
                                               const _Float16* __restrict__ Bsrc,
                                               const float* __restrict__ gate,
                                               _Float16* __restrict__ out) {
    __shared__ _Float16 As[64 * LDSP];
    __shared__ _Float16 Bs[64 * LDSP];
    WAVE_IDX();
    int j0 = blockIdx.x * 64, i0 = blockIdx.y * 64, b = blockIdx.z;
    const _Float16* Bb = Bsrc + (size_t)b * NN * CC;
    ACC_INIT();
    for (int kc = 0; kc < CC; kc += 64) {
        stage_rows(As, W, CC, i0, kc, tid);
        stage_rows(Bs, Bb, CC, j0, kc, tid);
        __syncthreads();
        mfma_tile(As, Bs, acc, wm, wn, x, qq);
        __syncthreads();
    }
#pragma unroll
    for (int ms = 0; ms < 2; ++ms) {
        int R0 = i0 + wm + ms * 16 + qq * 4;  // c
#pragma unroll
        for (int ns = 0; ns < 2; ++ns) {
            int Ccol = j0 + wn + ns * 16 + x; // n
#pragma unroll
            for (int e = 0; e < 4; ++e) {
                float v = acc[ms][ns][e] + bias[R0 + e];
                size_t idx = ((size_t)b * CC + R0 + e) * NN + Ccol;
                if (EPI == 1) v = gate[idx] / (1.f + __expf(-v));
                out[idx] = (_Float16)v;
            }
        }
    }
}

// ------------------------- energy -------------------------
// E[m][n] fp32 = sum_d qT[m][d]*kT[n][d].  K = 64 (single chunk).
// rad>0: only compute tiles overlapping the chunk-aligned row band of query tile i0.
__global__ __launch_bounds__(256) void k_energy(const _Float16* __restrict__ qT,
                                                const _Float16* __restrict__ kT,
                                                float* __restrict__ E, int rad) {
    __shared__ _Float16 As[64 * LDSP];
    __shared__ _Float16 Bs[64 * LDSP];
    WAVE_IDX();
    int j0 = blockIdx.x * 64, i0 = blockIdx.y * 64, b = blockIdx.z;
    if (rad > 0) {
        int hlo = i0 / WW, hhi = (i0 + 63) / WW;
        int h2lo = imax(0, hlo - rad), h2hi = imin(HH - 1, hhi + rad);
        int nlo = (h2lo * WW) & ~63;
        int nhi = imin(NN, ((h2hi + 1) * WW + 63) & ~63);
        if (j0 + 64 <= nlo || j0 >= nhi) return;
    }
    ACC_INIT();
    stage_rows(As, qT + (size_t)b * NN * DDQ, DDQ, i0, 0, tid);
    stage_rows(Bs, kT + (size_t)b * NN * DDQ, DDQ, j0, 0, tid);
    __syncthreads();
    mfma_tile(As, Bs, acc, wm, wn, x, qq);
#pragma unroll
    for (int ms = 0; ms < 2; ++ms) {
        int R0 = i0 + wm + ms * 16 + qq * 4;  // query m
#pragma unroll
        for (int ns = 0; ns < 2; ++ns) {
            int Ccol = j0 + wn + ns * 16 + x; // key n
#pragma unroll
            for (int e = 0; e < 4; ++e)
                E[((size_t)b * NN + R0 + e) * NN + Ccol] = acc[ms][ns][e];
        }
    }
}

// ------------------------- softmax (fp32 in -> fp16 attn, in place) -------------------------
// Reads fp32 E row, writes normalized fp16 weights over the row's leading bytes
// (fp16 row n at (half*)(E_row), row stride 2*NN halves). All reads complete before
// the aliasing writes (separated by the __syncthreads in the sum reduction).
// rad>0: FULL Chebyshev mask max(|dh|,|dw|)<=rad applied per element; zero fill over
// the chunk-aligned row-band union of the row's 64-row group so GEMM chunk reads are exact.
__global__ __launch_bounds__(256) void k_softmax(float* __restrict__ E, int rad) {
    __shared__ float red[256];
    int tid = threadIdx.x;
    int m = blockIdx.x, b = blockIdx.y;
    float* e = E + ((size_t)b * NN + m) * NN;
    _Float16* a = (_Float16*)e;
    int own_lo = 0, own_hi = NN, nlo = 0, nhi = NN;
    int mcol = m % WW;
    if (rad > 0) {
        int hm = m / WW;
        int oh_lo = imax(0, hm - rad), oh_hi = imin(HH - 1, hm + rad);
        own_lo = oh_lo * WW; own_hi = (oh_hi + 1) * WW;
        int i0 = m & ~63;
        int hlo = i0 / WW, hhi = (i0 + 63) / WW;
        int h2lo = imax(0, hlo - rad), h2hi = imin(HH - 1, hhi + rad);
        nlo = (h2lo * WW) & ~63;
        nhi = imin(NN, ((h2hi + 1) * WW + 63) & ~63);
    }
    float mx = -1e30f;
    for (int n = own_lo + tid; n < own_hi; n += 256) mx = fmaxf(mx, e[n]);
    red[tid] = mx; __syncthreads();
    for (int s = 128; s > 0; s >>= 1) {
        if (tid < s) red[tid] = fmaxf(red[tid], red[tid + s]);
        __syncthreads();
    }
    mx = red[0]; __syncthreads();

    float wloc[9];
    float ls = 0.f;
    int i = 0;
    for (int n = own_lo + tid; n < own_hi; n += 256, ++i) {
        float wv = __expf(e[n] - mx);
        if (rad > 0) {
            int nc = n % WW;
            int dc = mcol - nc; if (dc < 0) dc = -dc;
            if (dc > rad) wv = 0.f;       // column half of the Chebyshev mask
        }
        wloc[i] = wv; ls += wv;
    }
    red[tid] = ls; __syncthreads();
    for (int s = 128; s > 0; s >>= 1) {
        if (tid < s) red[tid] += red[tid + s];
        __syncthreads();
    }
    float inv = 1.f / red[0];
    i = 0;
    for (int n = own_lo + tid; n < own_hi; n += 256, ++i) a[n] = (_Float16)(wloc[i] * inv);
    for (int n = nlo + tid; n < own_lo; n += 256) a[n] = (_Float16)0.f;
    for (int n = own_hi + tid; n < nhi; n += 256) a[n] = (_Float16)0.f;
}

// ------------------------- attention apply -------------------------
// out[c][m] = gamma * sum_n A[c][n]*attn[m][n] + res[c][m]
// A fp16 [C][N]; attn fp16 rows at stride 2*NN halves (in-place over E); res fp32 [C][N].
__global__ __launch_bounds__(256) void k_attn(const _Float16* __restrict__ A,
                                              const _Float16* __restrict__ attn,
                                              const float* __restrict__ res,
                                              const float* __restrict__ gamma,
                                              float* __restrict__ outF,
                                              _Float16* __restrict__ outT, int rad) {
    __shared__ _Float16 As[64 * LDSP];
    __shared__ _Float16 Bs[64 * LDSP];
    WAVE_IDX();
    int j0 = blockIdx.x * 64, i0 = blockIdx.y * 64, b = blockIdx.z;
    int klo = 0, khi = NN;
    if (rad > 0) {
        int hlo = j0 / WW, hhi = (j0 + 63) / WW;
        int h2lo = imax(0, hlo - rad), h2hi = imin(HH - 1, hhi + rad);
        klo = (h2lo * WW) & ~63;
        khi = imin(NN, ((h2hi + 1) * WW + 63) & ~63);
    }
    const _Float16* Ab = A + (size_t)b * CC * NN;
    const _Float16* Tb = attn + (size_t)b * NN * (2 * NN);
    ACC_INIT();
    for (int kc = klo; kc < khi; kc += 64) {
        stage_rows(As, Ab, NN, i0, kc, tid);
        stage_rows(Bs, Tb, 2 * NN, j0, kc, tid);
        __syncthreads();
        mfma_tile(As, Bs, acc, wm, wn, x, qq);
        __syncthreads();
    }
    float g = gamma[0];
#pragma unroll
    for (int ms = 0; ms < 2; ++ms) {
        int R0 = i0 + wm + ms * 16 + qq * 4;   // c
#pragma unroll
        for (int ns = 0; ns < 2; ++ns) {
            int Ccol = j0 + wn + ns * 16 + x;  // m
            float v0 = g * acc[ms][ns][0] + res[((size_t)b * CC + R0 + 0) * NN + Ccol];
            float v1 = g * acc[ms][ns][1] + res[((size_t)b * CC + R0 + 1) * NN + Ccol];
            float v2 = g * acc[ms][ns][2] + res[((size_t)b * CC + R0 + 2) * NN + Ccol];
            float v3 = g * acc[ms][ns][3] + res[((size_t)b * CC + R0 + 3) * NN + Ccol];
            if (outT) {
                half4 t;
                t.x = (_Float16)v0; t.y = (_Float16)v1;
                t.z = (_Float16)v2; t.w = (_Float16)v3;
                *(half4*)(outT + ((size_t)b * NN + Ccol) * CC + R0) = t;
            }
            if (outF) {
                outF[((size_t)b * CC + R0 + 0) * NN + Ccol] = v0;
                outF[((size_t)b * CC + R0 + 1) * NN + Ccol] = v1;
                outF[((size_t)b * CC + R0 + 2) * NN + Ccol] = v2;
                outF[((size_t)b * CC + R0 + 3) * NN + Ccol] = v3;
            }
        }
    }
}

// ------------------------- 3x3 conv, implicit GEMM, fused BN+ReLU -------------------------
__global__ __launch_bounds__(256) void k_conv3(const _Float16* __restrict__ Arep,
                                               const _Float16* __restrict__ Tin,
                                               const float* __restrict__ bng,
                                               const float* __restrict__ bnb,
                                               const float* __restrict__ bnm,
                                               const float* __restrict__ bnv,
                                               float* __restrict__ outF,
                                               _Float16* __restrict__ outT) {
    __shared__ _Float16 As[64 * LDSP];
    __shared__ _Float16 Bs[64 * LDSP];
    WAVE_IDX();
    int j0 = blockIdx.x * 64, i0 = blockIdx.y * 64, b = blockIdx.z;
    const _Float16* Tb = Tin + (size_t)b * NN * CC;
    int mrow[2], mh[2], mw[2];
#pragma unroll
    for (int i = 0; i < 2; ++i) {
        int s = tid * 2 + i;
        int r = s >> 3;
        mrow[i] = r;
        int m = j0 + r;
        mh[i] = m / WW;
        mw[i] = m - mh[i] * WW;
    }
    ACC_INIT();
    for (int rt = 0; rt < 9; ++rt) {
        int dh = rt / 3 - 1, dw = rt - (rt / 3) * 3 - 1;
        const _Float16* Ar = Arep + (size_t)rt * CC * CC;
        for (int ci0 = 0; ci0 < CC; ci0 += 64) {
            stage_rows(As, Ar, CC, i0, ci0, tid);
#pragma unroll
            for (int i = 0; i < 2; ++i) {
                int s = tid * 2 + i;
                int off = (s & 7) << 3;
                int h2 = mh[i] + dh, w2 = mw[i] + dw;
                half8 val = {};
                if ((unsigned)h2 < (unsigned)HH && (unsigned)w2 < (unsigned)WW)
                    val = *(const half8*)(Tb + (size_t)(h2 * WW + w2) * CC + ci0 + off);
                *(half8*)(Bs + mrow[i] * LDSP + off) = val;
            }
            __syncthreads();
            mfma_tile(As, Bs, acc, wm, wn, x, qq);
            __syncthreads();
        }
    }
#pragma unroll
    for (int ms = 0; ms < 2; ++ms) {
        int R0 = i0 + wm + ms * 16 + qq * 4;  // co
        float sc[4], sh[4];
#pragma unroll
        for (int e = 0; e < 4; ++e) {
            sc[e] = bng[R0 + e] * rsqrtf(bnv[R0 + e] + 1e-5f);
            sh[e] = bnb[R0 + e] - bnm[R0 + e] * sc[e];
        }
#pragma unroll
        for (int ns = 0; ns < 2; ++ns) {
            int Ccol = j0 + wn + ns * 16 + x;  // m
            float v[4];
#pragma unroll
            for (int e = 0; e < 4; ++e) {
                float t = acc[ms][ns][e] * sc[e] + sh[e];
                v[e] = t > 0.f ? t : 0.f;
                outF[((size_t)b * CC + R0 + e) * NN + Ccol] = v[e];
            }
            half4 t4;
            t4.x = (_Float16)v[0]; t4.y = (_Float16)v[1];
            t4.z = (_Float16)v[2]; t4.w = (_Float16)v[3];
            *(half4*)(outT + ((size_t)b * NN + Ccol) * CC + R0) = t4;
        }
    }
}

// ---------------------------------------------------------------------------
extern "C" void kernel_launch(void* const* d_in, const int* in_sizes, int n_in,
                              void* d_out, int out_size, void* d_ws, size_t ws_size,
                              hipStream_t stream) {
    const float* xin  = (const float*)d_in[0];
    const float* Wq   = (const float*)d_in[1];
    const float* bq   = (const float*)d_in[2];
    const float* Wk   = (const float*)d_in[3];
    const float* bk   = (const float*)d_in[4];
    const float* Wv   = (const float*)d_in[5];
    const float* bv   = (const float*)d_in[6];
    const float* c1w  = (const float*)d_in[7];
    const float* bn1w = (const float*)d_in[8];
    const float* bn1b = (const float*)d_in[9];
    const float* bn1m = (const float*)d_in[10];
    const float* bn1v = (const float*)d_in[11];
    const float* c2w  = (const float*)d_in[12];
    const float* bn2w = (const float*)d_in[13];
    const float* bn2b = (const float*)d_in[14];
    const float* bn2m = (const float*)d_in[15];
    const float* bn2v = (const float*)d_in[16];
    const float* s1w  = (const float*)d_in[17];
    const float* s1b  = (const float*)d_in[18];
    const float* s2w  = (const float*)d_in[19];
    const float* s2b  = (const float*)d_in[20];
    const float* gamma  = (const float*)d_in[21];
    const float* gamma1 = (const float*)d_in[22];
    const float* gamma2 = (const float*)d_in[23];

    float* out = (float*)d_out;

    char* p = (char*)d_ws;
    float*    E     = (float*)p;    p += (size_t)BB * NN * NN * 4;   // 84.9 MB (attn fp16 in-place)
    _Float16* xT    = (_Float16*)p; p += (size_t)BB * NN * CC * 2;   // 9.4 MB
    _Float16* qT    = (_Float16*)p; p += (size_t)BB * NN * DDQ * 2;  // 1.2 MB
    _Float16* kT    = (_Float16*)p; p += (size_t)BB * NN * DDQ * 2;
    _Float16* vsB   = (_Float16*)p; p += (size_t)BB * CC * NN * 2;   // 9.4 MB (v, then s1/s2)
    _Float16* Tattn = (_Float16*)p; p += (size_t)BB * NN * CC * 2;
    _Float16* Tconv = (_Float16*)p; p += (size_t)BB * NN * CC * 2;
    float*    rR    = (float*)p;    p += (size_t)BB * CC * NN * 4;   // 18.9 MB (out0, then out1)
    _Float16* wq_h  = (_Float16*)p; p += (size_t)DDQ * CC * 2;
    _Float16* wk_h  = (_Float16*)p; p += (size_t)DDQ * CC * 2;
    _Float16* wv_h  = (_Float16*)p; p += (size_t)CC * CC * 2;
    _Float16* s1_h  = (_Float16*)p; p += (size_t)CC * CC * 2;
    _Float16* s2_h  = (_Float16*)p; p += (size_t)CC * CC * 2;
    _Float16* crep1 = (_Float16*)p; p += (size_t)9 * CC * CC * 2;    // 4.7 MB
    _Float16* crep2 = (_Float16*)p; p += (size_t)9 * CC * CC * 2;
    // total ~155 MB

    dim3 blk(256);

    // ---- prep ----
    k_f32_to_f16<<<dim3(128), blk, 0, stream>>>(Wq, wq_h, DDQ * CC);
    k_f32_to_f16<<<dim3(128), blk, 0, stream>>>(Wk, wk_h, DDQ * CC);
    k_f32_to_f16<<<dim3(1024), blk, 0, stream>>>(Wv, wv_h, CC * CC);
    k_f32_to_f16<<<dim3(1024), blk, 0, stream>>>(s1w, s1_h, CC * CC);
    k_f32_to_f16<<<dim3(1024), blk, 0, stream>>>(s2w, s2_h, CC * CC);
    k_repack_conv<<<dim3((9 * CC * CC + 255) / 256), blk, 0, stream>>>(c1w, crep1);
    k_repack_conv<<<dim3((9 * CC * CC + 255) / 256), blk, 0, stream>>>(c2w, crep2);
    k_transpose_x<<<dim3(NN / 32, CC / 32, BB), blk, 0, stream>>>(xin, xT);

    dim3 gQK(NN / 64, 2, BB);
    dim3 gC (NN / 64, CC / 64, BB);
    dim3 gE (NN / 64, NN / 64, BB);
    dim3 gSm(NN, BB);

    const _Float16* attnH = (const _Float16*)E;

    // projections
    k_qkproj<<<gQK, blk, 0, stream>>>(wq_h, wk_h, bq, bk, xT, qT, kT);
    k_cgemm<0><<<gC, blk, 0, stream>>>(wv_h, bv, xT, nullptr, vsB);

    // ---- stage 0: dense attention ----
    k_energy<<<gE, blk, 0, stream>>>(qT, kT, E, -1);
    k_softmax<<<gSm, blk, 0, stream>>>(E, -1);
    k_attn<<<gC, blk, 0, stream>>>(vsB, attnH, xin, gamma, nullptr, Tattn, -1);
    k_conv3<<<gC, blk, 0, stream>>>(crep1, Tattn, bn1w, bn1b, bn1m, bn1v, rR, Tconv);

    // ---- stage 1: radius-6 masked attention ----
    k_cgemm<1><<<gC, blk, 0, stream>>>(s1_h, s1b, Tconv, rR, vsB);
    k_energy<<<gE, blk, 0, stream>>>(qT, kT, E, 6);
    k_softmax<<<gSm, blk, 0, stream>>>(E, 6);
    k_attn<<<gC, blk, 0, stream>>>(vsB, attnH, rR, gamma1, nullptr, Tattn, 6);
    k_conv3<<<gC, blk, 0, stream>>>(crep2, Tattn, bn2w, bn2b, bn2m, bn2v, rR, Tconv);

    // ---- stage 2: radius-12 masked attention ----
    k_cgemm<1><<<gC, blk, 0, stream>>>(s2_h, s2b, Tconv, rR, vsB);
    k_energy<<<gE, blk, 0, stream>>>(qT, kT, E, 12);
    k_softmax<<<gSm, blk, 0, stream>>>(E, 12);
    k_attn<<<gC, blk, 0, stream>>>(vsB, attnH, rR, gamma2, out, nullptr, 12);
}

// Round 5
// 557.149 us; speedup vs baseline: 6.2744x; 1.1948x over previous
//
#include <hip/hip_runtime.h>
#include <math.h>

#define BB 4
#define CC 512
#define HH 48
#define WW 48
#define NN 2304      // H*W
#define DDQ 64       // C/8
#define LDSP 72      // padded LDS stride for the small (64^2) kernels
#define PW 50        // padded image width (W+2)
#define PROWS 2500   // (H+2)*(W+2)

typedef __attribute__((ext_vector_type(4))) float f32x4;
typedef __attribute__((ext_vector_type(8))) _Float16 half8;
typedef __attribute__((ext_vector_type(4))) _Float16 half4;

__device__ __forceinline__ int imax(int a, int b) { return a > b ? a : b; }
__device__ __forceinline__ int imin(int a, int b) { return a < b ? a : b; }
__device__ __forceinline__ int prow(int m) {       // interior padded row of spatial idx m
    int h = m / WW, w = m - h * WW;
    return (h + 1) * PW + (w + 1);
}

// ---- async global->LDS, 16B per lane, wave-uniform LDS base ----
typedef __attribute__((address_space(1))) unsigned int g_u32;
typedef __attribute__((address_space(3))) unsigned int l_u32;
__device__ __forceinline__ void gl16(const _Float16* g, _Float16* l) {
    __builtin_amdgcn_global_load_lds((g_u32*)g, (l_u32*)l, 16, 0, 0);
}

// ===========================================================================
// Big-tile GEMM core: 128(M) x 64(N) block tile, BK=64 halves, 256 threads.
// LDS: As[128][64], Bs[64][64] halves, XOR-swizzled: slot(r,kb) holds global
// kblock kb^(r&7)  (kb = 16B unit). Wave w computes 64x32 via 4x2 MFMA tiles.
// ===========================================================================
#define BWAVE_IDX()                                  \
    int tid = threadIdx.x;                           \
    int wave = tid >> 6, lane = tid & 63;            \
    int wm = (wave >> 1) * 64, wn = (wave & 1) * 32; \
    int x = lane & 15, qq = lane >> 4;

__device__ __forceinline__ half8 fragld(const _Float16* T, int r, int c) {
    int kb = c ^ (r & 7);
    return *(const half8*)(T + r * 64 + kb * 8);
}

__device__ __forceinline__ void btile(const _Float16* As, const _Float16* Bs,
                                      f32x4 acc[4][2], int wm, int wn, int x, int qq) {
#pragma unroll
    for (int ks = 0; ks < 2; ++ks) {
        int c = ks * 4 + qq;
        half8 a0 = fragld(As, wm + x, c);
        half8 a1 = fragld(As, wm + 16 + x, c);
        half8 a2 = fragld(As, wm + 32 + x, c);
        half8 a3 = fragld(As, wm + 48 + x, c);
        half8 b0 = fragld(Bs, wn + x, c);
        half8 b1 = fragld(Bs, wn + 16 + x, c);
        acc[0][0] = __builtin_amdgcn_mfma_f32_16x16x32_f16(a0, b0, acc[0][0], 0, 0, 0);
        acc[0][1] = __builtin_amdgcn_mfma_f32_16x16x32_f16(a0, b1, acc[0][1], 0, 0, 0);
        acc[1][0] = __builtin_amdgcn_mfma_f32_16x16x32_f16(a1, b0, acc[1][0], 0, 0, 0);
        acc[1][1] = __builtin_amdgcn_mfma_f32_16x16x32_f16(a1, b1, acc[1][1], 0, 0, 0);
        acc[2][0] = __builtin_amdgcn_mfma_f32_16x16x32_f16(a2, b0, acc[2][0], 0, 0, 0);
        acc[2][1] = __builtin_amdgcn_mfma_f32_16x16x32_f16(a2, b1, acc[2][1], 0, 0, 0);
        acc[3][0] = __builtin_amdgcn_mfma_f32_16x16x32_f16(a3, b0, acc[3][0], 0, 0, 0);
        acc[3][1] = __builtin_amdgcn_mfma_f32_16x16x32_f16(a3, b1, acc[3][1], 0, 0, 0);
    }
}

#define BACC_INIT()                                         \
    f32x4 zf = {0.f, 0.f, 0.f, 0.f};                        \
    f32x4 acc[4][2];                                        \
    _Pragma("unroll") for (int i_ = 0; i_ < 4; ++i_) {      \
        acc[i_][0] = zf; acc[i_][1] = zf; }

// per-call slot decomposition (A: 4 calls of 64 slots; B: 2 calls)
#define SLOT_A(i) int sb = (wave * 4 + (i)) * 64; int s = sb + lane; \
                  int r = s >> 3, kb = s & 7; int koff = ((kb ^ (r & 7)) << 3);
#define SLOT_B(i) int sb = (wave * 2 + (i)) * 64; int s = sb + lane; \
                  int r = s >> 3, kb = s & 7; int koff = ((kb ^ (r & 7)) << 3);

// ===========================================================================
// small 64^2 helpers (kept for qkproj / energy)
// ===========================================================================
__device__ __forceinline__ void stage_rows(_Float16* dst, const _Float16* __restrict__ src,
                                           int ld, int row0, int k0, int tid) {
#pragma unroll
    for (int i = 0; i < 2; ++i) {
        int s = tid * 2 + i;
        int r = s >> 3, off = (s & 7) << 3;
        *(half8*)(dst + r * LDSP + off) =
            *(const half8*)(src + (size_t)(row0 + r) * ld + k0 + off);
    }
}
__device__ __forceinline__ void mfma_tile(const _Float16* As, const _Float16* Bs,
                                          f32x4 acc[2][2], int wm, int wn, int x, int qq) {
#pragma unroll
    for (int ks = 0; ks < 2; ++ks) {
        int kof = ks * 32 + qq * 8;
        half8 a0 = *(const half8*)(As + (wm + x) * LDSP + kof);
        half8 a1 = *(const half8*)(As + (wm + 16 + x) * LDSP + kof);
        half8 b0 = *(const half8*)(Bs + (wn + x) * LDSP + kof);
        half8 b1 = *(const half8*)(Bs + (wn + 16 + x) * LDSP + kof);
        acc[0][0] = __builtin_amdgcn_mfma_f32_16x16x32_f16(a0, b0, acc[0][0], 0, 0, 0);
        acc[0][1] = __builtin_amdgcn_mfma_f32_16x16x32_f16(a0, b1, acc[0][1], 0, 0, 0);
        acc[1][0] = __builtin_amdgcn_mfma_f32_16x16x32_f16(a1, b0, acc[1][0], 0, 0, 0);
        acc[1][1] = __builtin_amdgcn_mfma_f32_16x16x32_f16(a1, b1, acc[1][1], 0, 0, 0);
    }
}
#define WAVE_IDX()                             \
    int tid = threadIdx.x;                     \
    int wave = tid >> 6, lane = tid & 63;      \
    int wm = (wave >> 1) * 32, wn = (wave & 1) * 32; \
    int x = lane & 15, qq = lane >> 4;
#define ACC_INIT()                             \
    f32x4 zf = {0.f, 0.f, 0.f, 0.f};           \
    f32x4 acc[2][2];                           \
    acc[0][0] = zf; acc[0][1] = zf; acc[1][0] = zf; acc[1][1] = zf;

// ------------------------- prep kernels -------------------------
__global__ __launch_bounds__(256) void k_f32_to_f16(const float* __restrict__ src,
                                                    _Float16* __restrict__ dst, int n) {
    for (int i = blockIdx.x * 256 + threadIdx.x; i < n; i += gridDim.x * 256)
        dst[i] = (_Float16)src[i];
}

// conv weight [co][ci][r=9] -> [r][co][ci] fp16
__global__ __launch_bounds__(256) void k_repack_conv(const float* __restrict__ w,
                                                     _Float16* __restrict__ dst) {
    int i = blockIdx.x * 256 + threadIdx.x;
    if (i >= 9 * CC * CC) return;
    int r = i / (CC * CC);
    int rem = i - r * CC * CC;
    int co = rem / CC, ci = rem - (rem / CC) * CC;
    dst[i] = (_Float16)w[((size_t)co * CC + ci) * 9 + r];
}

// x fp32 [b][c][n] -> xT fp16 [b][n][c]
__global__ __launch_bounds__(256) void k_transpose_x(const float* __restrict__ x,
                                                     _Float16* __restrict__ xT) {
    __shared__ float tile[32][33];
    int b = blockIdx.z;
    int c0 = blockIdx.y * 32, n0 = blockIdx.x * 32;
    int tx = threadIdx.x & 31, ty = threadIdx.x >> 5;
    const float* xb = x + (size_t)b * CC * NN;
#pragma unroll
    for (int rr = 0; rr < 32; rr += 8)
        tile[ty + rr][tx] = xb[(size_t)(c0 + ty + rr) * NN + n0 + tx];
    __syncthreads();
    _Float16* xTb = xT + (size_t)b * NN * CC;
#pragma unroll
    for (int rr = 0; rr < 32; rr += 8)
        xTb[(size_t)(n0 + ty + rr) * CC + c0 + tx] = (_Float16)tile[tx][ty + rr];
}

// ------------------------- q/k projection (64^2 path) -------------------------
__global__ __launch_bounds__(256) void k_qkproj(const _Float16* __restrict__ Wq,
                                                const _Float16* __restrict__ Wk,
                                                const float* __restrict__ bq,
                                                const float* __restrict__ bk,
                                                const _Float16* __restrict__ xT,
                                                _Float16* __restrict__ qT,
                                                _Float16* __restrict__ kT) {
    __shared__ _Float16 As[64 * LDSP];
    __shared__ _Float16 Bs[64 * LDSP];
    WAVE_IDX();
    int j0 = blockIdx.x * 64, b = blockIdx.z;
    const _Float16* Wp = blockIdx.y ? Wk : Wq;
    const float* bias = blockIdx.y ? bk : bq;
    _Float16* outT = blockIdx.y ? kT : qT;
    const _Float16* xTb = xT + (size_t)b * NN * CC;
    ACC_INIT();
    for (int kc = 0; kc < CC; kc += 64) {
        stage_rows(As, Wp, CC, 0, kc, tid);
        stage_rows(Bs, xTb, CC, j0, kc, tid);
        __syncthreads();
        mfma_tile(As, Bs, acc, wm, wn, x, qq);
        __syncthreads();
    }
#pragma unroll
    for (int ms = 0; ms < 2; ++ms) {
        int R0 = wm + ms * 16 + qq * 4;
#pragma unroll
        for (int ns = 0; ns < 2; ++ns) {
            int Ccol = j0 + wn + ns * 16 + x;
            half4 t;
            t.x = (_Float16)(acc[ms][ns][0] + bias[R0 + 0]);
            t.y = (_Float16)(acc[ms][ns][1] + bias[R0 + 1]);
            t.z = (_Float16)(acc[ms][ns][2] + bias[R0 + 2]);
            t.w = (_Float16)(acc[ms][ns][3] + bias[R0 + 3]);
            *(half4*)(outT + ((size_t)b * NN + Ccol) * DDQ + R0) = t;
        }
    }
}

// ------------------------- C x C GEMM, big tile -------------------------
// out[c][n] fp16. EPI=0: acc+bias (v-proj, B=xT unpadded).
// EPI=1: sigmoid(acc+bias)*gate (gates, B=Tpad padded rows).
template <int EPI, int PAD>
__global__ __launch_bounds__(256) void k_cgemm(const _Float16* __restrict__ W,
                                               const float* __restrict__ bias,
                                               const _Float16* __restrict__ Bsrc,
                                               const float* __restrict__ gate,
                                               _Float16* __restrict__ out) {
    __shared__ _Float16 As[128 * 64];
    __shared__ _Float16 Bs[64 * 64];
    BWAVE_IDX();
    int j0 = blockIdx.x * 64, i0 = blockIdx.y * 128, b = blockIdx.z;
    const _Float16* Bb = Bsrc + (size_t)b * (PAD ? (size_t)PROWS * CC : (size_t)NN * CC);

    const _Float16* aSrc[4]; int aOf[4];
#pragma unroll
    for (int i = 0; i < 4; ++i) {
        SLOT_A(i);
        aSrc[i] = W + (size_t)(i0 + r) * CC + koff;
        aOf[i] = sb * 8;
    }
    const _Float16* bSrc[2]; int bOf[2];
#pragma unroll
    for (int i = 0; i < 2; ++i) {
        SLOT_B(i);
        int row = PAD ? prow(j0 + r) : (j0 + r);
        bSrc[i] = Bb + (size_t)row * CC + koff;
        bOf[i] = sb * 8;
    }
    BACC_INIT();
    for (int kc = 0; kc < CC; kc += 64) {
        __syncthreads();
#pragma unroll
        for (int i = 0; i < 4; ++i) gl16(aSrc[i] + kc, As + aOf[i]);
#pragma unroll
        for (int i = 0; i < 2; ++i) gl16(bSrc[i] + kc, Bs + bOf[i]);
        __syncthreads();
        btile(As, Bs, acc, wm, wn, x, qq);
    }
#pragma unroll
    for (int mt = 0; mt < 4; ++mt) {
        int R0 = i0 + wm + mt * 16 + qq * 4;
#pragma unroll
        for (int nt = 0; nt < 2; ++nt) {
            int Ccol = j0 + wn + nt * 16 + x;
#pragma unroll
            for (int e = 0; e < 4; ++e) {
                float v = acc[mt][nt][e] + bias[R0 + e];
                size_t idx = ((size_t)b * CC + R0 + e) * NN + Ccol;
                if (EPI == 1) v = gate[idx] / (1.f + __expf(-v));
                out[idx] = (_Float16)v;
            }
        }
    }
}

// ------------------------- energy (64^2 path, fp32 out) -------------------------
__global__ __launch_bounds__(256) void k_energy(const _Float16* __restrict__ qT,
                                                const _Float16* __restrict__ kT,
                                                float* __restrict__ E, int rad) {
    __shared__ _Float16 As[64 * LDSP];
    __shared__ _Float16 Bs[64 * LDSP];
    WAVE_IDX();
    int j0 = blockIdx.x * 64, i0 = blockIdx.y * 64, b = blockIdx.z;
    if (rad > 0) {
        int hlo = i0 / WW, hhi = (i0 + 63) / WW;
        int h2lo = imax(0, hlo - rad), h2hi = imin(HH - 1, hhi + rad);
        int nlo = (h2lo * WW) & ~63;
        int nhi = imin(NN, ((h2hi + 1) * WW + 63) & ~63);
        if (j0 + 64 <= nlo || j0 >= nhi) return;
    }
    ACC_INIT();
    stage_rows(As, qT + (size_t)b * NN * DDQ, DDQ, i0, 0, tid);
    stage_rows(Bs, kT + (size_t)b * NN * DDQ, DDQ, j0, 0, tid);
    __syncthreads();
    mfma_tile(As, Bs, acc, wm, wn, x, qq);
#pragma unroll
    for (int ms = 0; ms < 2; ++ms) {
        int R0 = i0 + wm + ms * 16 + qq * 4;
#pragma unroll
        for (int ns = 0; ns < 2; ++ns) {
            int Ccol = j0 + wn + ns * 16 + x;
#pragma unroll
            for (int e = 0; e < 4; ++e)
                E[((size_t)b * NN + R0 + e) * NN + Ccol] = acc[ms][ns][e];
        }
    }
}

// ------------------------- softmax (fp32 in -> fp16 attn, in place) -------------------------
__global__ __launch_bounds__(256) void k_softmax(float* __restrict__ E, int rad) {
    __shared__ float red[256];
    int tid = threadIdx.x;
    int m = blockIdx.x, b = blockIdx.y;
    float* e = E + ((size_t)b * NN + m) * NN;
    _Float16* a = (_Float16*)e;
    int own_lo = 0, own_hi = NN, nlo = 0, nhi = NN;
    int mcol = m % WW;
    if (rad > 0) {
        int hm = m / WW;
        int oh_lo = imax(0, hm - rad), oh_hi = imin(HH - 1, hm + rad);
        own_lo = oh_lo * WW; own_hi = (oh_hi + 1) * WW;
        int i0 = m & ~63;
        int hlo = i0 / WW, hhi = (i0 + 63) / WW;
        int h2lo = imax(0, hlo - rad), h2hi = imin(HH - 1, hhi + rad);
        nlo = (h2lo * WW) & ~63;
        nhi = imin(NN, ((h2hi + 1) * WW + 63) & ~63);
    }
    int v0 = own_lo >> 2, v1 = own_hi >> 2;  // float4 range (bounds are x48 -> /4 exact)

    float mx = -1e30f;
    for (int n4 = v0 + tid; n4 < v1; n4 += 256) {
        float4 v = *(const float4*)(e + n4 * 4);
        mx = fmaxf(fmaxf(fmaxf(mx, v.x), v.y), fmaxf(v.z, v.w));
    }
    red[tid] = mx; __syncthreads();
    for (int s = 128; s > 0; s >>= 1) {
        if (tid < s) red[tid] = fmaxf(red[tid], red[tid + s]);
        __syncthreads();
    }
    mx = red[0]; __syncthreads();

    f32x4 wloc[3];
    float ls = 0.f;
#pragma unroll
    for (int ii = 0; ii < 3; ++ii) {
        int n4 = v0 + tid + ii * 256;
        if (n4 < v1) {
            float4 v = *(const float4*)(e + n4 * 4);
            f32x4 w;
            w[0] = __expf(v.x - mx); w[1] = __expf(v.y - mx);
            w[2] = __expf(v.z - mx); w[3] = __expf(v.w - mx);
            if (rad > 0) {
                int cb = (n4 * 4) % WW;
#pragma unroll
                for (int j = 0; j < 4; ++j) {
                    int dc = mcol - (cb + j); if (dc < 0) dc = -dc;
                    if (dc > rad) w[j] = 0.f;
                }
            }
            wloc[ii] = w;
            ls += w[0] + w[1] + w[2] + w[3];
        }
    }
    red[tid] = ls; __syncthreads();
    for (int s = 128; s > 0; s >>= 1) {
        if (tid < s) red[tid] += red[tid + s];
        __syncthreads();
    }
    float inv = 1.f / red[0];
#pragma unroll
    for (int ii = 0; ii < 3; ++ii) {
        int n4 = v0 + tid + ii * 256;
        if (n4 < v1) {
            half4 h;
            h.x = (_Float16)(wloc[ii][0] * inv);
            h.y = (_Float16)(wloc[ii][1] * inv);
            h.z = (_Float16)(wloc[ii][2] * inv);
            h.w = (_Float16)(wloc[ii][3] * inv);
            *(half4*)(a + n4 * 4) = h;
        }
    }
    for (int n = nlo + tid; n < own_lo; n += 256) a[n] = (_Float16)0.f;
    for (int n = own_hi + tid; n < nhi; n += 256) a[n] = (_Float16)0.f;
}

// ------------------------- attention apply, big tile -------------------------
// out[c][m] = gamma * sum_n A[c][n]*attn[m][n] + res[c][m]
// A fp16 [C][N]; attn fp16 rows stride 2*NN halves (in-place over E); res fp32 [C][N].
// outF fp32 [b][c][m] and/or outT fp16 padded [b][prow(m)][c] may be null.
__global__ __launch_bounds__(256) void k_attn(const _Float16* __restrict__ A,
                                              const _Float16* __restrict__ attn,
                                              const float* __restrict__ res,
                                              const float* __restrict__ gamma,
                                              float* __restrict__ outF,
                                              _Float16* __restrict__ outT, int rad) {
    __shared__ _Float16 As[128 * 64];
    __shared__ _Float16 Bs[64 * 64];
    BWAVE_IDX();
    int j0 = blockIdx.x * 64, i0 = blockIdx.y * 128, b = blockIdx.z;
    int klo = 0, khi = NN;
    if (rad > 0) {
        int hlo = j0 / WW, hhi = (j0 + 63) / WW;
        int h2lo = imax(0, hlo - rad), h2hi = imin(HH - 1, hhi + rad);
        klo = (h2lo * WW) & ~63;
        khi = imin(NN, ((h2hi + 1) * WW + 63) & ~63);
    }
    const _Float16* Ab = A + (size_t)b * CC * NN;
    const _Float16* Tb = attn + (size_t)b * NN * (2 * NN);

    const _Float16* aSrc[4]; int aOf[4];
#pragma unroll
    for (int i = 0; i < 4; ++i) {
        SLOT_A(i);
        aSrc[i] = Ab + (size_t)(i0 + r) * NN + koff;
        aOf[i] = sb * 8;
    }
    const _Float16* bSrc[2]; int bOf[2];
#pragma unroll
    for (int i = 0; i < 2; ++i) {
        SLOT_B(i);
        bSrc[i] = Tb + (size_t)(j0 + r) * (2 * NN) + koff;
        bOf[i] = sb * 8;
    }
    BACC_INIT();
    for (int kc = klo; kc < khi; kc += 64) {
        __syncthreads();
#pragma unroll
        for (int i = 0; i < 4; ++i) gl16(aSrc[i] + kc, As + aOf[i]);
#pragma unroll
        for (int i = 0; i < 2; ++i) gl16(bSrc[i] + kc, Bs + bOf[i]);
        __syncthreads();
        btile(As, Bs, acc, wm, wn, x, qq);
    }
    float g = gamma[0];
#pragma unroll
    for (int mt = 0; mt < 4; ++mt) {
        int R0 = i0 + wm + mt * 16 + qq * 4;
#pragma unroll
        for (int nt = 0; nt < 2; ++nt) {
            int Ccol = j0 + wn + nt * 16 + x;
            float v[4];
#pragma unroll
            for (int e = 0; e < 4; ++e)
                v[e] = g * acc[mt][nt][e] + res[((size_t)b * CC + R0 + e) * NN + Ccol];
            if (outT) {
                half4 t;
                t.x = (_Float16)v[0]; t.y = (_Float16)v[1];
                t.z = (_Float16)v[2]; t.w = (_Float16)v[3];
                *(half4*)(outT + ((size_t)b * PROWS + prow(Ccol)) * CC + R0) = t;
            }
            if (outF) {
#pragma unroll
                for (int e = 0; e < 4; ++e)
                    outF[((size_t)b * CC + R0 + e) * NN + Ccol] = v[e];
            }
        }
    }
}

// ------------------------- 3x3 conv, big tile, fused BN+ReLU -------------------------
// Tpad fp16 [b][PROWS][C] (zero border), Arep fp16 [r][co][ci].
// outF fp32 [b][co][m], outT fp16 padded [b][prow(m)][co].
__global__ __launch_bounds__(256) void k_conv3(const _Float16* __restrict__ Arep,
                                               const _Float16* __restrict__ Tpad,
                                               const float* __restrict__ bng,
                                               const float* __restrict__ bnb,
                                               const float* __restrict__ bnm,
                                               const float* __restrict__ bnv,
                                               float* __restrict__ outF,
                                               _Float16* __restrict__ outT) {
    __shared__ _Float16 As[128 * 64];
    __shared__ _Float16 Bs[64 * 64];
    BWAVE_IDX();
    int j0 = blockIdx.x * 64, i0 = blockIdx.y * 128, b = blockIdx.z;
    const _Float16* Tb = Tpad + (size_t)b * PROWS * CC;

    size_t aRow[4]; int aOf[4];
#pragma unroll
    for (int i = 0; i < 4; ++i) {
        SLOT_A(i);
        aRow[i] = (size_t)(i0 + r) * CC + koff;
        aOf[i] = sb * 8;
    }
    int bPr[2], bKoff[2], bOf[2];
#pragma unroll
    for (int i = 0; i < 2; ++i) {
        SLOT_B(i);
        bPr[i] = prow(j0 + r);
        bKoff[i] = koff;
        bOf[i] = sb * 8;
    }
    BACC_INIT();
#pragma unroll
    for (int rt = 0; rt < 9; ++rt) {
        int dh = rt / 3 - 1, dw = rt - (rt / 3) * 3 - 1;
        int shift = dh * PW + dw;
        const _Float16* Ar = Arep + (size_t)rt * CC * CC;
        for (int ci0 = 0; ci0 < CC; ci0 += 64) {
            __syncthreads();
#pragma unroll
            for (int i = 0; i < 4; ++i) gl16(Ar + aRow[i] + ci0, As + aOf[i]);
#pragma unroll
            for (int i = 0; i < 2; ++i)
                gl16(Tb + (size_t)(bPr[i] + shift) * CC + ci0 + bKoff[i], Bs + bOf[i]);
            __syncthreads();
            btile(As, Bs, acc, wm, wn, x, qq);
        }
    }
#pragma unroll
    for (int mt = 0; mt < 4; ++mt) {
        int R0 = i0 + wm + mt * 16 + qq * 4;
        float sc[4], sh[4];
#pragma unroll
        for (int e = 0; e < 4; ++e) {
            sc[e] = bng[R0 + e] * rsqrtf(bnv[R0 + e] + 1e-5f);
            sh[e] = bnb[R0 + e] - bnm[R0 + e] * sc[e];
        }
#pragma unroll
        for (int nt = 0; nt < 2; ++nt) {
            int Ccol = j0 + wn + nt * 16 + x;
            float v[4];
#pragma unroll
            for (int e = 0; e < 4; ++e) {
                float t = acc[mt][nt][e] * sc[e] + sh[e];
                v[e] = t > 0.f ? t : 0.f;
                outF[((size_t)b * CC + R0 + e) * NN + Ccol] = v[e];
            }
            half4 t4;
            t4.x = (_Float16)v[0]; t4.y = (_Float16)v[1];
            t4.z = (_Float16)v[2]; t4.w = (_Float16)v[3];
            *(half4*)(outT + ((size_t)b * PROWS + prow(Ccol)) * CC + R0) = t4;
        }
    }
}

// ---------------------------------------------------------------------------
extern "C" void kernel_launch(void* const* d_in, const int* in_sizes, int n_in,
                              void* d_out, int out_size, void* d_ws, size_t ws_size,
                              hipStream_t stream) {
    const float* xin  = (const float*)d_in[0];
    const float* Wq   = (const float*)d_in[1];
    const float* bq   = (const float*)d_in[2];
    const float* Wk   = (const float*)d_in[3];
    const float* bk   = (const float*)d_in[4];
    const float* Wv   = (const float*)d_in[5];
    const float* bv   = (const float*)d_in[6];
    const float* c1w  = (const float*)d_in[7];
    const float* bn1w = (const float*)d_in[8];
    const float* bn1b = (const float*)d_in[9];
    const float* bn1m = (const float*)d_in[10];
    const float* bn1v = (const float*)d_in[11];
    const float* c2w  = (const float*)d_in[12];
    const float* bn2w = (const float*)d_in[13];
    const float* bn2b = (const float*)d_in[14];
    const float* bn2m = (const float*)d_in[15];
    const float* bn2v = (const float*)d_in[16];
    const float* s1w  = (const float*)d_in[17];
    const float* s1b  = (const float*)d_in[18];
    const float* s2w  = (const float*)d_in[19];
    const float* s2b  = (const float*)d_in[20];
    const float* gamma  = (const float*)d_in[21];
    const float* gamma1 = (const float*)d_in[22];
    const float* gamma2 = (const float*)d_in[23];

    float* out = (float*)d_out;

    char* p = (char*)d_ws;
    float*    E     = (float*)p;    p += (size_t)BB * NN * NN * 4;      // 84.9 MB
    _Float16* xT    = (_Float16*)p; p += (size_t)BB * NN * CC * 2;      // 9.4 MB
    _Float16* qT    = (_Float16*)p; p += (size_t)BB * NN * DDQ * 2;
    _Float16* kT    = (_Float16*)p; p += (size_t)BB * NN * DDQ * 2;
    _Float16* vsB   = (_Float16*)p; p += (size_t)BB * CC * NN * 2;      // 9.4 MB
    _Float16* TattnP= (_Float16*)p; p += (size_t)BB * PROWS * CC * 2;   // 10.2 MB
    _Float16* TconvP= (_Float16*)p; p += (size_t)BB * PROWS * CC * 2;   // 10.2 MB
    float*    rR    = (float*)p;    p += (size_t)BB * CC * NN * 4;      // 18.9 MB
    _Float16* wq_h  = (_Float16*)p; p += (size_t)DDQ * CC * 2;
    _Float16* wk_h  = (_Float16*)p; p += (size_t)DDQ * CC * 2;
    _Float16* wv_h  = (_Float16*)p; p += (size_t)CC * CC * 2;
    _Float16* s1_h  = (_Float16*)p; p += (size_t)CC * CC * 2;
    _Float16* s2_h  = (_Float16*)p; p += (size_t)CC * CC * 2;
    _Float16* crep1 = (_Float16*)p; p += (size_t)9 * CC * CC * 2;
    _Float16* crep2 = (_Float16*)p; p += (size_t)9 * CC * CC * 2;
    // total ~156 MB

    dim3 blk(256);

    // zero padded activation buffers (borders must read as 0 for taps)
    hipMemsetAsync(TattnP, 0, (size_t)BB * PROWS * CC * 2, stream);
    hipMemsetAsync(TconvP, 0, (size_t)BB * PROWS * CC * 2, stream);

    // ---- prep ----
    k_f32_to_f16<<<dim3(128), blk, 0, stream>>>(Wq, wq_h, DDQ * CC);
    k_f32_to_f16<<<dim3(128), blk, 0, stream>>>(Wk, wk_h, DDQ * CC);
    k_f32_to_f16<<<dim3(1024), blk, 0, stream>>>(Wv, wv_h, CC * CC);
    k_f32_to_f16<<<dim3(1024), blk, 0, stream>>>(s1w, s1_h, CC * CC);
    k_f32_to_f16<<<dim3(1024), blk, 0, stream>>>(s2w, s2_h, CC * CC);
    k_repack_conv<<<dim3((9 * CC * CC + 255) / 256), blk, 0, stream>>>(c1w, crep1);
    k_repack_conv<<<dim3((9 * CC * CC + 255) / 256), blk, 0, stream>>>(c2w, crep2);
    k_transpose_x<<<dim3(NN / 32, CC / 32, BB), blk, 0, stream>>>(xin, xT);

    dim3 gQK(NN / 64, 2, BB);
    dim3 gE (NN / 64, NN / 64, BB);
    dim3 gSm(NN, BB);
    dim3 gBig(NN / 64, CC / 128, BB);   // (36, 4, 4) = 576 blocks

    const _Float16* attnH = (const _Float16*)E;

    // projections
    k_qkproj<<<gQK, blk, 0, stream>>>(wq_h, wk_h, bq, bk, xT, qT, kT);
    k_cgemm<0, 0><<<gBig, blk, 0, stream>>>(wv_h, bv, xT, nullptr, vsB);

    // ---- stage 0: dense attention ----
    k_energy<<<gE, blk, 0, stream>>>(qT, kT, E, -1);
    k_softmax<<<gSm, blk, 0, stream>>>(E, -1);
    k_attn<<<gBig, blk, 0, stream>>>(vsB, attnH, xin, gamma, nullptr, TattnP, -1);
    k_conv3<<<gBig, blk, 0, stream>>>(crep1, TattnP, bn1w, bn1b, bn1m, bn1v, rR, TconvP);

    // ---- stage 1: radius-6 masked attention ----
    k_cgemm<1, 1><<<gBig, blk, 0, stream>>>(s1_h, s1b, TconvP, rR, vsB);
    k_energy<<<gE, blk, 0, stream>>>(qT, kT, E, 6);
    k_softmax<<<gSm, blk, 0, stream>>>(E, 6);
    k_attn<<<gBig, blk, 0, stream>>>(vsB, attnH, rR, gamma1, nullptr, TattnP, 6);
    k_conv3<<<gBig, blk, 0, stream>>>(crep2, TattnP, bn2w, bn2b, bn2m, bn2v, rR, TconvP);

    // ---- stage 2: radius-12 masked attention ----
    k_cgemm<1, 1><<<gBig, blk, 0, stream>>>(s2_h, s2b, TconvP, rR, vsB);
    k_energy<<<gE, blk, 0, stream>>>(qT, kT, E, 12);
    k_softmax<<<gSm, blk, 0, stream>>>(E, 12);
    k_attn<<<gBig, blk, 0, stream>>>(vsB, attnH, rR, gamma2, out, nullptr, 12);
}